// Round 10
// baseline (1467.809 us; speedup 1.0000x reference)
//
#include <hip/hip_runtime.h>
#include <hip/hip_bf16.h>

#define N_ENT 100000
#define HDIM 128
#define NE 200000
#define NR 460
#define NSTEP 4
#define SLOPE 0.22916666666666666f
#define NPAD 100352            // N_ENT padded to 1024 multiple (98*1024)
#define SCAN_NB 98

typedef __attribute__((ext_vector_type(8))) short short8;
typedef __attribute__((ext_vector_type(4))) short s4v;
typedef __attribute__((ext_vector_type(4))) float f32x4;

__device__ __forceinline__ float sigm(float x) { return 1.0f / (1.0f + __expf(-x)); }
__device__ __forceinline__ short f2bs(float f) {
    __hip_bfloat16 b = __float2bfloat16(f);
    short s; __builtin_memcpy(&s, &b, 2); return s;
}
__device__ __forceinline__ float bs2f(short s) {
    union { unsigned int u; float f; } c;
    c.u = ((unsigned int)(unsigned short)s) << 16;
    return c.f;
}

// ---------------------------------------------------------------------------
__global__ void zero_int_kernel(int* __restrict__ p, int n)
{
    int i = blockIdx.x * 256 + threadIdx.x;
    if (i < n) p[i] = 0;
}

__global__ void diag_kernel(float* o, float v)
{
    if (threadIdx.x == 0) o[0] = v;
}

// ---------------------------------------------------------------------------
// CSR build: histogram -> 3-phase exclusive scan -> fill
// ---------------------------------------------------------------------------
__global__ void hist_kernel(const int* __restrict__ dst, int* __restrict__ cnt)
{
    int e = blockIdx.x * 256 + threadIdx.x;
    if (e < NE) atomicAdd(&cnt[dst[e]], 1);
}

__global__ __launch_bounds__(256)
void scan1_kernel(const int* __restrict__ cnt, int* __restrict__ rowptr,
                  int* __restrict__ bsum)
{
    __shared__ int ts[256];
    int b = blockIdx.x, t = threadIdx.x;
    int base = b * 1024 + t * 4;
    int4 v = *(const int4*)&cnt[base];
    int s = v.x + v.y + v.z + v.w;
    ts[t] = s;
    __syncthreads();
    for (int off = 1; off < 256; off <<= 1) {
        int x = 0;
        if (t >= off) x = ts[t - off];
        __syncthreads();
        if (t >= off) ts[t] += x;
        __syncthreads();
    }
    int excl = ts[t] - s;
    if (t == 255) bsum[b] = ts[t];
    rowptr[base + 0] = excl;
    rowptr[base + 1] = excl + v.x;
    rowptr[base + 2] = excl + v.x + v.y;
    rowptr[base + 3] = excl + v.x + v.y + v.z;
}

__global__ __launch_bounds__(128)
void scan2_kernel(int* __restrict__ bsum, int nb)
{
    __shared__ int ts[128];
    int t = threadIdx.x;
    int v = (t < nb) ? bsum[t] : 0;
    ts[t] = v;
    __syncthreads();
    for (int off = 1; off < 128; off <<= 1) {
        int x = 0;
        if (t >= off) x = ts[t - off];
        __syncthreads();
        if (t >= off) ts[t] += x;
        __syncthreads();
    }
    if (t < nb) bsum[t] = ts[t] - v;   // exclusive
}

__global__ __launch_bounds__(256)
void scan3_kernel(int* __restrict__ rowptr, const int* __restrict__ bsum)
{
    int b = blockIdx.x, t = threadIdx.x;
    int add = bsum[b];
    int base = b * 1024 + t * 4;
    rowptr[base + 0] += add;
    rowptr[base + 1] += add;
    rowptr[base + 2] += add;
    rowptr[base + 3] += add;
}

__global__ void fill_kernel(const int* __restrict__ dst,
                            const int* __restrict__ rowptr,
                            int* __restrict__ c2, int* __restrict__ eidx)
{
    int e = blockIdx.x * 256 + threadIdx.x;
    if (e < NE) {
        int d = dst[e];
        int p = atomicAdd(&c2[d], 1);
        eidx[rowptr[d] + p] = e;
    }
}

// ---------------------------------------------------------------------------
// Prep: GRU weight transposes (f32) + bf16 B^T buffers for the MFMA GEMMs.
// ---------------------------------------------------------------------------
__global__ void prep_kernel(
    const float* __restrict__ emb_rel,
    const float* __restrict__ Wx, const float* __restrict__ Wh,
    const float* __restrict__ Wn1, const float* __restrict__ Wl1,
    const float* __restrict__ Wn2, const float* __restrict__ Wl2,
    const float* __restrict__ tgW, const float* __restrict__ gateW,
    const float* __restrict__ tdW,
    float* __restrict__ rel,
    float* __restrict__ WxT, float* __restrict__ WhT,
    short* __restrict__ BT1, short* __restrict__ BT2,
    short* __restrict__ BTe1, short* __restrict__ BTe2,
    short* __restrict__ BTe3)
{
    int tid = blockIdx.x * blockDim.x + threadIdx.x;
    int nthr = gridDim.x * blockDim.x;
    for (int i = tid; i < NR * HDIM; i += nthr)
        rel[i] = emb_rel[i];
    for (int i = tid; i < 384 * 256; i += nthr) {
        int r = i >> 8, c = i & 255;
        WxT[c * 384 + r] = Wx[i];
    }
    for (int i = tid; i < 384 * 128; i += nthr) {
        int r = i >> 7, c = i & 127;
        WhT[c * 384 + r] = Wh[i];
    }
    for (int i = tid; i < 128 * 256; i += nthr) {   // layer BTs: [x|h]@[Wn;Wl]
        int n = i >> 8, k = i & 255;
        float v1 = (k < 128) ? Wn1[k * 128 + n] : Wl1[(k - 128) * 128 + n];
        float v2 = (k < 128) ? Wn2[k * 128 + n] : Wl2[(k - 128) * 128 + n];
        BT1[n * 256 + k] = f2bs(v1);
        BT2[n * 256 + k] = f2bs(v2);
    }
    for (int i = tid; i < 128 * 128; i += nthr) {   // E1 (transpose), E3 (direct)
        int n = i >> 7, k = i & 127;
        BTe1[n * 128 + k] = f2bs(tgW[k * 128 + n]);
        BTe3[n * 128 + k] = f2bs(tdW[n * 128 + k]);
    }
    for (int i = tid; i < 128 * 256; i += nthr) {   // E2 (direct)
        int n = i >> 8, k = i & 255;
        BTe2[n * 256 + k] = f2bs(gateW[n * 256 + k]);
    }
}

// ---------------------------------------------------------------------------
// h0 = l2norm(dynamic_emb); one wave per row.
// ---------------------------------------------------------------------------
__global__ __launch_bounds__(64)
void norm_init_kernel(const float* __restrict__ emb, float* __restrict__ h)
{
    int row = blockIdx.x, lane = threadIdx.x;
    float v0 = emb[row * HDIM + lane];
    float v1 = emb[row * HDIM + 64 + lane];
    float s = v0 * v0 + v1 * v1;
    #pragma unroll
    for (int off = 32; off; off >>= 1) s += __shfl_xor(s, off);
    float invn = 1.0f / fmaxf(sqrtf(s), 1e-12f);
    h[row * HDIM + lane] = v0 * invn;
    h[row * HDIM + 64 + lane] = v1 * invn;
}

// ---------------------------------------------------------------------------
// GRUCell relation evolution (f32 GEMV — tiny: 460 rows).
// ---------------------------------------------------------------------------
__global__ __launch_bounds__(128)
void gru_kernel(float* rel, const float* __restrict__ emb_rel,
                const float* __restrict__ WxT, const float* __restrict__ WhT,
                const float* __restrict__ bx, const float* __restrict__ bh)
{
    __shared__ __align__(16) float x[256];
    __shared__ __align__(16) float hh[128];
    int b = blockIdx.x, j = threadIdx.x;
    float hj = rel[b * HDIM + j];
    x[j] = emb_rel[b * HDIM + j];
    x[128 + j] = hj;
    hh[j] = hj;
    __syncthreads();
    float xr = 0, xz = 0, xn = 0, hr = 0, hz = 0, hn = 0;
    for (int k = 0; k < 256; k++) {
        float xv = x[k];
        const float* w = &WxT[k * 384];
        xr += xv * w[j]; xz += xv * w[128 + j]; xn += xv * w[256 + j];
    }
    for (int k = 0; k < 128; k++) {
        float hv = hh[k];
        const float* w = &WhT[k * 384];
        hr += hv * w[j]; hz += hv * w[128 + j]; hn += hv * w[256 + j];
    }
    float r = sigm(xr + bx[j] + hr + bh[j]);
    float z = sigm(xz + bx[128 + j] + hz + bh[128 + j]);
    float n = tanhf(xn + bx[256 + j] + r * (hn + bh[256 + j]));
    rel[b * HDIM + j] = (1.0f - z) * n + z * hj;
}

// ---------------------------------------------------------------------------
// CSR gather for rows [lo,hi): aggb[r-lo] = bf16((sum_e h[src]+rel[et])/deg).
// ---------------------------------------------------------------------------
__global__ __launch_bounds__(256)
void gather_kernel(const int* __restrict__ src, const int* __restrict__ et,
                   const int* __restrict__ eidx, const int* __restrict__ rowptr,
                   const float* __restrict__ hin, const float* __restrict__ rel,
                   short* __restrict__ aggb, int lo, int hi)
{
    int idx = blockIdx.x * 256 + threadIdx.x;
    int r = lo + (idx >> 6);
    int i2 = (idx & 63) * 2;
    if (r >= hi) return;
    int p0 = rowptr[r], p1 = rowptr[r + 1];
    float v0 = 0.0f, v1 = 0.0f;
    for (int p = p0; p < p1; p++) {
        int e = eidx[p];
        int s = src[e], rt = et[e];
        const float* ph = &hin[(long)s * HDIM + i2];
        const float* pr = &rel[rt * HDIM + i2];
        v0 += ph[0] + pr[0];
        v1 += ph[1] + pr[1];
    }
    float rdeg = (p1 > p0) ? 1.0f / (float)(p1 - p0) : 0.0f;
    unsigned int pk = (unsigned int)(unsigned short)f2bs(v0 * rdeg)
                    | ((unsigned int)(unsigned short)f2bs(v1 * rdeg) << 16);
    *(unsigned int*)&aggb[(long)(r - lo) * HDIM + i2] = pk;
}

// ---------------------------------------------------------------------------
// Layer MFMA GEMM: out = rrelu([aggb | h] @ BT^T).  aggb bf16 (direct
// A-fragments); B-fragments from L2-hot global (no LDS).
// ---------------------------------------------------------------------------
__global__ __launch_bounds__(256, 2)
void layer_gemm(const short* __restrict__ aggb, const float* __restrict__ hin,
                const short* __restrict__ BTg, float* __restrict__ out,
                int lo, int hi)
{
    const int tid = threadIdx.x;
    const int lane = tid & 63;
    const int wv = tid >> 6;
    const int m = lane & 15, q = lane >> 4;
    const int rowBase = lo + blockIdx.x * 256 + wv * 64;

    f32x4 acc[4][8];
    #pragma unroll
    for (int rt = 0; rt < 4; rt++)
        #pragma unroll
        for (int ct = 0; ct < 8; ct++)
            acc[rt][ct] = (f32x4)0.0f;

    for (int kc = 0; kc < 8; kc++) {
        short8 a[4];
        #pragma unroll
        for (int rt = 0; rt < 4; rt++) {
            int row = rowBase + rt * 16 + m;
            int k0 = kc * 32 + q * 8;
            if (row < hi) {
                if (kc < 4) {
                    a[rt] = *(const short8*)&aggb[(long)(row - lo) * HDIM + k0];
                } else {
                    const float* p = &hin[(long)row * HDIM + (k0 - 128)];
                    float4 u0 = *(const float4*)p;
                    float4 u1 = *(const float4*)(p + 4);
                    short8 t;
                    t[0]=f2bs(u0.x); t[1]=f2bs(u0.y); t[2]=f2bs(u0.z); t[3]=f2bs(u0.w);
                    t[4]=f2bs(u1.x); t[5]=f2bs(u1.y); t[6]=f2bs(u1.z); t[7]=f2bs(u1.w);
                    a[rt] = t;
                }
            } else {
                short8 t;
                #pragma unroll
                for (int i = 0; i < 8; i++) t[i] = 0;
                a[rt] = t;
            }
        }
        short8 b[8];
        #pragma unroll
        for (int ct = 0; ct < 8; ct++)
            b[ct] = *(const short8*)&BTg[(ct * 16 + m) * 256 + kc * 32 + q * 8];
        #pragma unroll
        for (int rt = 0; rt < 4; rt++)
            #pragma unroll
            for (int ct = 0; ct < 8; ct++)
                acc[rt][ct] = __builtin_amdgcn_mfma_f32_16x16x32_bf16(
                    a[rt], b[ct], acc[rt][ct], 0, 0, 0);
    }

    #pragma unroll
    for (int rt = 0; rt < 4; rt++) {
        #pragma unroll
        for (int rg = 0; rg < 4; rg++) {
            int row = rowBase + rt * 16 + q * 4 + rg;
            if (row >= hi) continue;
            #pragma unroll
            for (int ct = 0; ct < 8; ct++) {
                int col = ct * 16 + m;
                float c = acc[rt][ct][rg];
                c = c >= 0.0f ? c : SLOPE * c;
                out[(long)row * HDIM + col] = c;
            }
        }
    }
}

// ---------------------------------------------------------------------------
// Fused epilogue v4 — wave-autonomous, ZERO block barriers.
// 128 thr = 2 waves; each wave owns 16 rows x 128 cols with a private LDS
// slice (cs/hs bf16).  Cross-lane exchange stays within the wave: per-wave
// in-order DS execution makes write->read safe; wave_barrier() pins compiler
// ordering.  d = cs - hs computed on the fly (no ds buffer).  f32 output
// staged on an overlay of the wave's dead cs/hs region.
// LDS 17.5 KB -> 9 blocks/CU = 18 free-running waves.
// ---------------------------------------------------------------------------
#define ES 136                 // bf16 row stride (shorts)
__global__ __launch_bounds__(128)
void fused_epi_kernel(const float* __restrict__ cur, const float* __restrict__ hprev,
                      const short* __restrict__ BTe1, const short* __restrict__ BTe2,
                      const short* __restrict__ BTe3,
                      const float* __restrict__ bt, const float* __restrict__ bg,
                      const float* __restrict__ btd,
                      float* __restrict__ outp)
{
    __shared__ __align__(16) short sm[2 * 2 * 16 * ES];   // [wave][cs|hs]
    __shared__ float invn_s[32];
    const int tid = threadIdx.x;
    const int wv = tid >> 6, lane = tid & 63;
    short* csW = sm + wv * (2 * 16 * ES);
    short* hsW = csW + 16 * ES;
    float* fw = (float*)csW;            // overlay (valid after cs/hs dead)
    const int row0g = blockIdx.x * 32 + wv * 16;
    const int m = lane & 15, q = lane >> 4;

    // ---- stage this wave's 16 rows of cur/h as bf16
    #pragma unroll
    for (int it = 0; it < 8; it++) {
        int idx = it * 64 + lane;
        int r = idx >> 5, c4 = (idx & 31) * 4;
        const float* pc = &cur[(long)(row0g + r) * HDIM + c4];
        const float* ph = &hprev[(long)(row0g + r) * HDIM + c4];
        float4 c = *(const float4*)pc;
        float4 h = *(const float4*)ph;
        s4v tc, th;
        tc[0]=f2bs(c.x); tc[1]=f2bs(c.y); tc[2]=f2bs(c.z); tc[3]=f2bs(c.w);
        th[0]=f2bs(h.x); th[1]=f2bs(h.y); th[2]=f2bs(h.z); th[3]=f2bs(h.w);
        *(s4v*)&csW[r * ES + c4] = tc;
        *(s4v*)&hsW[r * ES + c4] = th;
    }
    __builtin_amdgcn_wave_barrier();

    // ---- row inverse norms (wave's own 16 rows)
    #pragma unroll
    for (int r = 0; r < 16; r++) {
        float a = bs2f(csW[r * ES + lane]);
        float b = bs2f(csW[r * ES + 64 + lane]);
        float s = a * a + b * b;
        #pragma unroll
        for (int off = 32; off; off >>= 1) s += __shfl_xor(s, off);
        if (lane == 0) invn_s[wv * 16 + r] = 1.0f / fmaxf(sqrtf(s), 1e-12f);
    }
    __builtin_amdgcn_wave_barrier();

    // ---- pre-scale: cs <- bf16(cur * invn)
    #pragma unroll
    for (int it = 0; it < 8; it++) {
        int idx = it * 64 + lane;
        int r = idx >> 5, c4 = (idx & 31) * 4;
        float inv = invn_s[wv * 16 + r];
        s4v x = *(s4v*)&csW[r * ES + c4];
        s4v y;
        #pragma unroll
        for (int j = 0; j < 4; j++) y[j] = f2bs(bs2f(x[j]) * inv);
        *(s4v*)&csW[r * ES + c4] = y;
    }
    __builtin_amdgcn_wave_barrier();

    // ---- E1: acc = cur_n @ Wt
    f32x4 acc[8];
    #pragma unroll
    for (int ct = 0; ct < 8; ct++) acc[ct] = (f32x4)0.0f;
    #pragma unroll
    for (int kc = 0; kc < 4; kc++) {
        int k0 = kc * 32 + q * 8;
        short8 a = *(const short8*)&csW[m * ES + k0];
        #pragma unroll
        for (int ct = 0; ct < 8; ct++) {
            short8 b = *(const short8*)&BTe1[(ct * 16 + m) * 128 + k0];
            acc[ct] = __builtin_amdgcn_mfma_f32_16x16x32_bf16(a, b, acc[ct], 0, 0, 0);
        }
    }
    __builtin_amdgcn_wave_barrier();

    #pragma unroll
    for (int ct = 0; ct < 8; ct++) {
        int col = ct * 16 + m;
        #pragma unroll
        for (int rg = 0; rg < 4; rg++) {
            int rl = q * 4 + rg;
            float tw = sigm(acc[ct][rg] + bt[col]);
            float curn = bs2f(csW[rl * ES + col]);
            float hv = bs2f(hsW[rl * ES + col]);
            csW[rl * ES + col] = f2bs(tw * curn + (1.0f - tw) * hv);   // h1
        }
    }
    __builtin_amdgcn_wave_barrier();

    // ---- E2: acc = [h1|h] @ Wg^T
    #pragma unroll
    for (int ct = 0; ct < 8; ct++) acc[ct] = (f32x4)0.0f;
    #pragma unroll
    for (int kc = 0; kc < 8; kc++) {
        int k0 = kc * 32 + q * 8;
        short8 a = (kc < 4) ? *(const short8*)&csW[m * ES + k0]
                            : *(const short8*)&hsW[m * ES + (k0 - 128)];
        #pragma unroll
        for (int ct = 0; ct < 8; ct++) {
            short8 b = *(const short8*)&BTe2[(ct * 16 + m) * 256 + k0];
            acc[ct] = __builtin_amdgcn_mfma_f32_16x16x32_bf16(a, b, acc[ct], 0, 0, 0);
        }
    }
    __builtin_amdgcn_wave_barrier();

    #pragma unroll
    for (int ct = 0; ct < 8; ct++) {
        int col = ct * 16 + m;
        #pragma unroll
        for (int rg = 0; rg < 4; rg++) {
            int rl = q * 4 + rg;
            float g = sigm(acc[ct][rg] + bg[col]);
            float h1v = bs2f(csW[rl * ES + col]);
            float hv = bs2f(hsW[rl * ES + col]);
            csW[rl * ES + col] = f2bs(g * h1v + (1.0f - g) * hv);     // h2
        }
    }
    __builtin_amdgcn_wave_barrier();

    // ---- E3: acc = (h2 - h) @ Wtd^T  (d computed on the fly)
    #pragma unroll
    for (int ct = 0; ct < 8; ct++) acc[ct] = (f32x4)0.0f;
    #pragma unroll
    for (int kc = 0; kc < 4; kc++) {
        int k0 = kc * 32 + q * 8;
        short8 c8 = *(const short8*)&csW[m * ES + k0];
        short8 h8 = *(const short8*)&hsW[m * ES + k0];
        short8 a;
        #pragma unroll
        for (int j = 0; j < 8; j++) a[j] = f2bs(bs2f(c8[j]) - bs2f(h8[j]));
        #pragma unroll
        for (int ct = 0; ct < 8; ct++) {
            short8 b = *(const short8*)&BTe3[(ct * 16 + m) * 128 + k0];
            acc[ct] = __builtin_amdgcn_mfma_f32_16x16x32_bf16(a, b, acc[ct], 0, 0, 0);
        }
    }
    __builtin_amdgcn_wave_barrier();

    // ---- read all h2 into regs, then write f32 output to overlay
    float h2r[8][4];
    #pragma unroll
    for (int ct = 0; ct < 8; ct++) {
        int col = ct * 16 + m;
        #pragma unroll
        for (int rg = 0; rg < 4; rg++)
            h2r[ct][rg] = bs2f(csW[(q * 4 + rg) * ES + col]);
    }
    __builtin_amdgcn_wave_barrier();

    #pragma unroll
    for (int ct = 0; ct < 8; ct++) {
        int col = ct * 16 + m;
        #pragma unroll
        for (int rg = 0; rg < 4; rg++) {
            int rl = q * 4 + rg;
            float td = fmaxf(acc[ct][rg] + btd[col], 0.0f);
            fw[rl * 132 + col] = h2r[ct][rg] + td;
        }
    }
    __builtin_amdgcn_wave_barrier();

    #pragma unroll
    for (int it = 0; it < 8; it++) {
        int idx = it * 64 + lane;
        int r = idx >> 5, c4 = (idx & 31) * 4;
        *(float4*)&outp[(long)(row0g + r) * HDIM + c4] = *(float4*)&fw[r * 132 + c4];
    }
}

// ---------------------------------------------------------------------------
extern "C" void kernel_launch(void* const* d_in, const int* in_sizes, int n_in,
                              void* d_out, int out_size, void* d_ws, size_t ws_size,
                              hipStream_t stream)
{
    const int* src = (const int*)d_in[0];
    const int* dst = (const int*)d_in[1];
    const int* ety = (const int*)d_in[2];
    const float* dyn     = (const float*)d_in[3];
    const float* emb_rel = (const float*)d_in[4];
    const float* Wn1     = (const float*)d_in[5];
    const float* Wl1     = (const float*)d_in[6];
    const float* Wn2     = (const float*)d_in[7];
    const float* Wl2     = (const float*)d_in[8];
    const float* gWx     = (const float*)d_in[9];
    const float* gWh     = (const float*)d_in[10];
    const float* gbx     = (const float*)d_in[11];
    const float* gbh     = (const float*)d_in[12];
    const float* gateW   = (const float*)d_in[13];
    const float* gateb   = (const float*)d_in[14];
    const float* tdW     = (const float*)d_in[15];
    const float* tdb     = (const float*)d_in[16];
    const float* tgW     = (const float*)d_in[17];
    const float* tgb     = (const float*)d_in[18];

    const long NH = (long)N_ENT * HDIM;          // 12,800,000
    float* ws = (float*)d_ws;
    long off = 0;
    float* A    = ws + off; off += NH;           // h state
    float* B    = ws + off; off += NH;           // layer1 out
    float* rel  = ws + off; off += (long)NR * HDIM;
    float* WxT  = ws + off; off += 98304;
    float* WhT  = ws + off; off += 49152;
    short* BT1  = (short*)(ws + off); off += 16384;   // 128x256 bf16
    short* BT2  = (short*)(ws + off); off += 16384;
    short* BTe1 = (short*)(ws + off); off += 8192;    // 128x128 bf16
    short* BTe2 = (short*)(ws + off); off += 16384;
    short* BTe3 = (short*)(ws + off); off += 8192;
    int* rowptr = (int*)(ws + off); off += NPAD;
    int* cnt    = (int*)(ws + off); off += NPAD;      // cnt, cnt2 contiguous
    int* cnt2   = (int*)(ws + off); off += NPAD;
    int* eidx   = (int*)(ws + off); off += 200704;
    int* bsum   = (int*)(ws + off); off += 128;
    short* aggb = (short*)(ws + off);            // chunk*128 bf16
    float* C    = (float*)d_out;                 // layer2 out (= cur)

    const long avail = (long)(ws_size / 4) - off;
    const int cand[5] = {100000, 50000, 25008, 12512, 6256};
    int chunk = -1;
    for (int c = 0; c < 5; c++)
        if (avail >= (long)cand[c] * 64) { chunk = cand[c]; break; }

    if (chunk < 0) {
        diag_kernel<<<1, 64, 0, stream>>>((float*)d_out, (float)ws_size);
        return;
    }

    prep_kernel<<<256, 256, 0, stream>>>(
        emb_rel, gWx, gWh, Wn1, Wl1, Wn2, Wl2, tgW, gateW, tdW,
        rel, WxT, WhT, BT1, BT2, BTe1, BTe2, BTe3);

    norm_init_kernel<<<N_ENT, 64, 0, stream>>>(dyn, A);

    const int egrid = (NE + 255) / 256;          // 782 blocks
    const int fe_grid = N_ENT / 32;              // 3125 blocks

    for (int t = 0; t < NSTEP; t++) {
        const int* st = src + (long)t * NE;
        const int* dt = dst + (long)t * NE;
        const int* et = ety + (long)t * NE;

        // ---- CSR build for this step's graph (shared by both layers)
        zero_int_kernel<<<(2 * NPAD + 255) / 256, 256, 0, stream>>>(cnt, 2 * NPAD);
        hist_kernel<<<egrid, 256, 0, stream>>>(dt, cnt);
        scan1_kernel<<<SCAN_NB, 256, 0, stream>>>(cnt, rowptr, bsum);
        scan2_kernel<<<1, 128, 0, stream>>>(bsum, SCAN_NB);
        scan3_kernel<<<SCAN_NB, 256, 0, stream>>>(rowptr, bsum);
        fill_kernel<<<egrid, 256, 0, stream>>>(dt, rowptr, cnt2, eidx);

        gru_kernel<<<NR, 128, 0, stream>>>(rel, emb_rel, WxT, WhT, gbx, gbh);

        // layer 1: A -> B
        for (int lo = 0; lo < N_ENT; lo += chunk) {
            int hi = lo + chunk > N_ENT ? N_ENT : lo + chunk;
            gather_kernel<<<((hi - lo) * 64 + 255) / 256, 256, 0, stream>>>(
                st, et, eidx, rowptr, A, rel, aggb, lo, hi);
            layer_gemm<<<(hi - lo + 255) / 256, 256, 0, stream>>>(
                aggb, A, BT1, B, lo, hi);
        }
        // layer 2: B -> C
        for (int lo = 0; lo < N_ENT; lo += chunk) {
            int hi = lo + chunk > N_ENT ? N_ENT : lo + chunk;
            gather_kernel<<<((hi - lo) * 64 + 255) / 256, 256, 0, stream>>>(
                st, et, eidx, rowptr, B, rel, aggb, lo, hi);
            layer_gemm<<<(hi - lo + 255) / 256, 256, 0, stream>>>(
                aggb, B, BT2, C, lo, hi);
        }

        // fused epilogue: (C, A) -> A (t<3) or d_out == C (t=3)
        float* outp = (t == NSTEP - 1) ? C : A;
        fused_epi_kernel<<<fe_grid, 128, 0, stream>>>(
            C, A, BTe1, BTe2, BTe3, tgb, gateb, tdb, outp);
    }
}